// Round 14
// baseline (323.178 us; speedup 1.0000x reference)
//
#include <hip/hip_runtime.h>
#include <math.h>

constexpr int NE = 16;   // experts
constexpr int NG = 4;    // groups
#define MARGIN 1e-4

typedef __attribute__((ext_vector_type(8))) short bf16x8;
typedef __attribute__((ext_vector_type(4))) float f32x4;

__device__ __forceinline__ unsigned short f2bf_rne(float f) {
    unsigned u = __float_as_uint(f);
    unsigned r = (u + 0x7fffu + ((u >> 16) & 1u)) >> 16;
    return (unsigned short)r;
}

// prep: wt fp32 [k][e] (for K2) + w split into bf16 hi/lo in ORIGINAL [e][k] layout
__global__ __launch_bounds__(256)
void w_prep_kernel(const float* __restrict__ w, float* __restrict__ wt,
                   unsigned short* __restrict__ whi, unsigned short* __restrict__ wlo,
                   int dim, int n) {
    int id = blockIdx.x * 256 + threadIdx.x;
    if (id < n) {
        int e = id / dim;
        int k = id - e * dim;
        float f = w[id];
        wt[(size_t)k * NE + e] = f;
        unsigned short h = f2bf_rne(f);
        float back = __uint_as_float(((unsigned)h) << 16);
        whi[id] = h;
        wlo[id] = f2bf_rne(f - back);
    }
}

struct RouteR { double v1, v2; int i1, i2; double mg, mo, ms; };

__device__ __forceinline__ RouteR route_epilogue(const double* tot,
                                                 const float* w1b,
                                                 const float* rbias)
{
    double logit[NE];
    double m = -INFINITY;
#pragma unroll
    for (int e = 0; e < NE; ++e) {
        logit[e] = tot[e] + (double)w1b[e];
        m = fmax(m, logit[e]);
    }
    double ssum = 0.0, p[NE];
#pragma unroll
    for (int e = 0; e < NE; ++e) { p[e] = exp(logit[e] - m); ssum += p[e]; }
    double inv = 1.0 / ssum, sc[NE];
#pragma unroll
    for (int e = 0; e < NE; ++e) sc[e] = p[e] * inv + (double)rbias[e];

    double gm[NG];
#pragma unroll
    for (int g = 0; g < NG; ++g) {
        double a = fmax(sc[g * 4 + 0], sc[g * 4 + 1]);
        double b = fmax(sc[g * 4 + 2], sc[g * 4 + 3]);
        gm[g] = fmax(a, b);
    }
    int g1 = 0;
#pragma unroll
    for (int g = 1; g < NG; ++g) if (gm[g] > gm[g1]) g1 = g;
    int g2 = (g1 == 0) ? 1 : 0;
#pragma unroll
    for (int g = 0; g < NG; ++g) if (g != g1 && gm[g] > gm[g2]) g2 = g;
    double gm3 = -INFINITY;
#pragma unroll
    for (int g = 0; g < NG; ++g)
        if (g != g1 && g != g2 && gm[g] > gm3) gm3 = gm[g];

    RouteR r;
    r.v1 = -INFINITY; r.i1 = 0;
#pragma unroll
    for (int e = 0; e < NE; ++e) {
        int g = e >> 2;
        bool keep = (g == g1) || (g == g2);
        if (keep && sc[e] > r.v1) { r.v1 = sc[e]; r.i1 = e; }
    }
    r.v2 = -INFINITY; r.i2 = 0;
#pragma unroll
    for (int e = 0; e < NE; ++e) {
        int g = e >> 2;
        bool keep = ((g == g1) || (g == g2)) && (e != r.i1);
        if (keep && sc[e] > r.v2) { r.v2 = sc[e]; r.i2 = e; }
    }
    double v3 = -INFINITY;
#pragma unroll
    for (int e = 0; e < NE; ++e) {
        int g = e >> 2;
        bool keep = ((g == g1) || (g == g2)) && (e != r.i1) && (e != r.i2);
        if (keep && sc[e] > v3) v3 = sc[e];
    }
    r.mg = gm[g2] - gm3;
    r.mo = r.v1 - r.v2;
    r.ms = r.v2 - v3;
    return r;
}

// K1: bf16-split MFMA GEMM. 4 waves/block, 16 tokens/wave, no LDS in main loop.
__global__ __launch_bounds__(256)
void k1_mfma(const float* __restrict__ x,
             const unsigned short* __restrict__ whi,
             const unsigned short* __restrict__ wlo,
             const float* __restrict__ w1b,
             const float* __restrict__ rbias,
             float* __restrict__ dout,
             int* __restrict__ fcount,
             int* __restrict__ flist,
             int n_tokens, int dim)
{
    __shared__ float scl[4][16][NE + 1];
    const int tid  = threadIdx.x;
    const int wid  = tid >> 6;
    const int lane = tid & 63;
    const int m    = lane & 15;        // A row (token) & B col (expert)
    const int kg   = lane >> 4;        // k-group 0..3
    const long tok0 = (long)blockIdx.x * 64 + wid * 16;
    const int nst = dim / 32;          // 128 K-steps

    const float* xp = x + (tok0 + m) * (size_t)dim + kg * 8;
    const unsigned short* whp = whi + (size_t)m * dim + kg * 8;  // B[k][e]=w[e][k]
    const unsigned short* wlp = wlo + (size_t)m * dim + kg * 8;

    f32x4 acc = {0.f, 0.f, 0.f, 0.f};

    float4 xa = *(const float4*)(xp);
    float4 xb = *(const float4*)(xp + 4);
    bf16x8 wh = *(const bf16x8*)(whp);
    bf16x8 wl = *(const bf16x8*)(wlp);

    for (int c = 0; c < nst; ++c) {
        float4 nxa = xa, nxb = xb;
        bf16x8 nwh = wh, nwl = wl;
        if (c + 1 < nst) {
            const float* xn = xp + (size_t)(c + 1) * 32;
            nxa = *(const float4*)(xn);
            nxb = *(const float4*)(xn + 4);
            nwh = *(const bf16x8*)(whp + (size_t)(c + 1) * 32);
            nwl = *(const bf16x8*)(wlp + (size_t)(c + 1) * 32);
        }

        float xf[8] = {xa.x, xa.y, xa.z, xa.w, xb.x, xb.y, xb.z, xb.w};
        bf16x8 xhi, xlo;
#pragma unroll
        for (int j = 0; j < 8; ++j) {
            float f = xf[j];
            unsigned short h = f2bf_rne(f);
            float back = __uint_as_float(((unsigned)h) << 16);
            xhi[j] = (short)h;
            xlo[j] = (short)f2bf_rne(f - back);
        }

        acc = __builtin_amdgcn_mfma_f32_16x16x32_bf16(xhi, wh, acc, 0, 0, 0);
        acc = __builtin_amdgcn_mfma_f32_16x16x32_bf16(xlo, wh, acc, 0, 0, 0);
        acc = __builtin_amdgcn_mfma_f32_16x16x32_bf16(xhi, wl, acc, 0, 0, 0);

        xa = nxa; xb = nxb; wh = nwh; wl = nwl;
    }

    // D: row(token-in-wave)=kg*4+j, col(expert)=m  [m89-verified mapping]
#pragma unroll
    for (int j = 0; j < 4; ++j)
        scl[wid][kg * 4 + j][m] = acc[j];
    // same-wave DS write->read ordering; no barrier needed

    if (lane < 16) {
        double tot[NE];
#pragma unroll
        for (int e = 0; e < NE; ++e) tot[e] = (double)scl[wid][lane][e];
        RouteR r = route_epilogue(tot, w1b, rbias);
        long tok = tok0 + lane;

        double mmin = fmin(r.mg, fmin(r.mo, r.ms));
        if (mmin < MARGIN) {
            int idx = atomicAdd(fcount, 1);
            if (idx < n_tokens) flist[idx] = (int)tok;
        }
        float2 vv; vv.x = (float)r.v1; vv.y = (float)r.v2;
        *(float2*)(dout + tok * 2) = vv;
        float2 iv; iv.x = (float)r.i1; iv.y = (float)r.i2;
        *(float2*)(dout + (long)n_tokens * 2 + tok * 2) = iv;
    }
}

// K2: authoritative fp64 recompute, one wave per flagged token (proven r12/13)
__global__ __launch_bounds__(256)
void k2_recheck(const float* __restrict__ x,
                const float* __restrict__ wt,
                const float* __restrict__ w1b,
                const float* __restrict__ rbias,
                float* __restrict__ dout,
                const int* __restrict__ fcount,
                const int* __restrict__ flist,
                int n_tokens, int dim)
{
    const int tid  = threadIdx.x;
    const int lane = tid & 63;
    const int wavesPerBlock = blockDim.x >> 6;
    const int wglobal = blockIdx.x * wavesPerBlock + (tid >> 6);
    const int nwaves  = gridDim.x * wavesPerBlock;
    int nf = *fcount;
    if (nf > n_tokens) nf = n_tokens;
    const int nq = dim / 256;

    for (int i = wglobal; i < nf; i += nwaves) {
        const int t = flist[i];
        const float* xr = x + (size_t)t * dim;

        double part[NE];
#pragma unroll
        for (int e = 0; e < NE; ++e) part[e] = 0.0;

        for (int q = 0; q < nq; ++q) {
            float4 xv = *(const float4*)(xr + q * 256 + lane * 4);
#pragma unroll
            for (int j = 0; j < 4; ++j) {
                int k = q * 256 + lane * 4 + j;
                double xd = (double)((const float*)&xv)[j];
                const float* wr = wt + (size_t)k * NE;
#pragma unroll
                for (int e = 0; e < NE; ++e)
                    part[e] = fma(xd, (double)wr[e], part[e]);
            }
        }

#pragma unroll
        for (int off = 1; off < 64; off <<= 1) {
#pragma unroll
            for (int e = 0; e < NE; ++e)
                part[e] += __shfl_xor(part[e], off, 64);
        }

        RouteR r = route_epilogue(part, w1b, rbias);
        if (lane == 0) {
            float2 vv; vv.x = (float)r.v1; vv.y = (float)r.v2;
            *(float2*)(dout + (long)t * 2) = vv;
            float2 iv; iv.x = (float)r.i1; iv.y = (float)r.i2;
            *(float2*)(dout + (long)n_tokens * 2 + (long)t * 2) = iv;
        }
    }
}

// ---------------- fallback (round-9 proven fp64 structure, w gathered) ------
__global__ __launch_bounds__(256)
void router_fallback(const float* __restrict__ x,
                     const float* __restrict__ w1w,
                     const float* __restrict__ w1b,
                     const float* __restrict__ rbias,
                     float* __restrict__ dout,
                     int n_tokens, int dim)
{
    __shared__ double wbuf4[4][16][NE];
    const int tid  = threadIdx.x;
    const int uwid = __builtin_amdgcn_readfirstlane(tid >> 6);
    const int lane = tid & 63;
    const int slice = dim / 4;
    const int nst  = slice / 16;
    const long tokA = (long)blockIdx.x * 128 + lane;
    const long tokB = tokA + 64;
    const float* xA = x + tokA * (size_t)dim + (size_t)uwid * slice;
    const float* xB = x + tokB * (size_t)dim + (size_t)uwid * slice;

    double accA[NE], accB[NE];
#pragma unroll
    for (int e = 0; e < NE; ++e) { accA[e] = 0.0; accB[e] = 0.0; }

    float4 a0 = *(const float4*)(xA + 0), a1 = *(const float4*)(xA + 4);
    float4 a2 = *(const float4*)(xA + 8), a3 = *(const float4*)(xA + 12);
    float4 b0 = *(const float4*)(xB + 0), b1 = *(const float4*)(xB + 4);
    float4 b2 = *(const float4*)(xB + 8), b3 = *(const float4*)(xB + 12);
    float4 wreg;
    {
        const int i0 = lane * 4;
#pragma unroll
        for (int j = 0; j < 4; ++j) {
            int i = i0 + j;
            ((float*)&wreg)[j] = w1w[(size_t)(i & 15) * dim + uwid * slice + (i >> 4)];
        }
    }

    for (int c = 0; c < nst; ++c) {
        {
            double* dst = &wbuf4[uwid][0][0] + lane * 4;
            dst[0] = (double)wreg.x;  dst[1] = (double)wreg.y;
            dst[2] = (double)wreg.z;  dst[3] = (double)wreg.w;
        }
        float4 na0=a0,na1=a1,na2=a2,na3=a3,nb0=b0,nb1=b1,nb2=b2,nb3=b3;
        if (c + 1 < nst) {
            const float* pa = xA + (c + 1) * 16;
            const float* pb = xB + (c + 1) * 16;
            na0 = *(const float4*)(pa + 0);  na1 = *(const float4*)(pa + 4);
            na2 = *(const float4*)(pa + 8);  na3 = *(const float4*)(pa + 12);
            nb0 = *(const float4*)(pb + 0);  nb1 = *(const float4*)(pb + 4);
            nb2 = *(const float4*)(pb + 8);  nb3 = *(const float4*)(pb + 12);
            const int kb = uwid * slice + (c + 1) * 16;
            const int i0 = lane * 4;
#pragma unroll
            for (int j = 0; j < 4; ++j) {
                int i = i0 + j;
                ((float*)&wreg)[j] = w1w[(size_t)(i & 15) * dim + kb + (i >> 4)];
            }
        }
        float fa[16], fb[16];
        fa[0]=a0.x; fa[1]=a0.y; fa[2]=a0.z; fa[3]=a0.w;
        fa[4]=a1.x; fa[5]=a1.y; fa[6]=a1.z; fa[7]=a1.w;
        fa[8]=a2.x; fa[9]=a2.y; fa[10]=a2.z; fa[11]=a2.w;
        fa[12]=a3.x; fa[13]=a3.y; fa[14]=a3.z; fa[15]=a3.w;
        fb[0]=b0.x; fb[1]=b0.y; fb[2]=b0.z; fb[3]=b0.w;
        fb[4]=b1.x; fb[5]=b1.y; fb[6]=b1.z; fb[7]=b1.w;
        fb[8]=b2.x; fb[9]=b2.y; fb[10]=b2.z; fb[11]=b2.w;
        fb[12]=b3.x; fb[13]=b3.y; fb[14]=b3.z; fb[15]=b3.w;
#pragma unroll
        for (int kk = 0; kk < 16; ++kk) {
            double xa_ = (double)fa[kk];
            double xb_ = (double)fb[kk];
#pragma unroll
            for (int ep = 0; ep < NE / 2; ++ep) {
                double2 wv = *(const double2*)&wbuf4[uwid][kk][ep * 2];
                accA[ep*2+0] = fma(xa_, wv.x, accA[ep*2+0]);
                accA[ep*2+1] = fma(xa_, wv.y, accA[ep*2+1]);
                accB[ep*2+0] = fma(xb_, wv.x, accB[ep*2+0]);
                accB[ep*2+1] = fma(xb_, wv.y, accB[ep*2+1]);
            }
        }
        a0=na0; a1=na1; a2=na2; a3=na3;
        b0=nb0; b1=nb1; b2=nb2; b3=nb3;
    }

    __syncthreads();
    __shared__ double red[3][2][64][NE + 1];
    if (uwid != 0) {
#pragma unroll
        for (int e = 0; e < NE; ++e) {
            red[uwid - 1][0][lane][e] = accA[e];
            red[uwid - 1][1][lane][e] = accB[e];
        }
    }
    __syncthreads();
    if (uwid != 0) return;

#pragma unroll
    for (int t = 0; t < 2; ++t) {
        double tot[NE];
#pragma unroll
        for (int e = 0; e < NE; ++e) {
            double a = (t == 0) ? accA[e] : accB[e];
            tot[e] = ((a + red[0][t][lane][e]) + red[1][t][lane][e])
                     + red[2][t][lane][e];
        }
        RouteR r = route_epilogue(tot, w1b, rbias);
        long tok = (t == 0) ? tokA : tokB;
        float2 vv; vv.x = (float)r.v1; vv.y = (float)r.v2;
        *(float2*)(dout + tok * 2) = vv;
        float2 iv; iv.x = (float)r.i1; iv.y = (float)r.i2;
        *(float2*)(dout + (long)n_tokens * 2 + tok * 2) = iv;
    }
}

extern "C" void kernel_launch(void* const* d_in, const int* in_sizes, int n_in,
                              void* d_out, int out_size, void* d_ws, size_t ws_size,
                              hipStream_t stream)
{
    const float* x   = (const float*)d_in[0];
    const float* w1w = (const float*)d_in[1];
    const float* w1b = (const float*)d_in[2];
    const float* rb  = (const float*)d_in[3];
    float* out = (float*)d_out;

    const int ne       = in_sizes[2];            // 16
    const int dim      = in_sizes[1] / ne;       // 4096
    const int n_tokens = in_sizes[0] / dim;      // 65536

    const int nW = dim * ne;                     // 65536 w elements
    const size_t WT_BYTES  = (size_t)nW * sizeof(float);          // 256 KB
    const size_t WHI_OFF   = WT_BYTES;
    const size_t WLO_OFF   = WHI_OFF + (size_t)nW * 2;            // +128 KB
    const size_t COUNT_OFF = WLO_OFF + (size_t)nW * 2;            // +128 KB
    const size_t LIST_OFF  = COUNT_OFF + 128;
    const size_t need = LIST_OFF + (size_t)n_tokens * sizeof(int);

    if (ws_size >= need) {
        float* wt            = (float*)d_ws;
        unsigned short* whi  = (unsigned short*)((char*)d_ws + WHI_OFF);
        unsigned short* wlo  = (unsigned short*)((char*)d_ws + WLO_OFF);
        int* fcount          = (int*)((char*)d_ws + COUNT_OFF);
        int* flist           = (int*)((char*)d_ws + LIST_OFF);

        hipMemsetAsync(fcount, 0, sizeof(int), stream);
        hipLaunchKernelGGL(w_prep_kernel, dim3((nW + 255) / 256), dim3(256),
                           0, stream, w1w, wt, whi, wlo, dim, nW);
        hipLaunchKernelGGL(k1_mfma, dim3(n_tokens / 64), dim3(256),
                           0, stream, x, whi, wlo, w1b, rb, out, fcount, flist,
                           n_tokens, dim);
        hipLaunchKernelGGL(k2_recheck, dim3(256), dim3(256),
                           0, stream, x, wt, w1b, rb, out, fcount, flist,
                           n_tokens, dim);
    } else {
        hipLaunchKernelGGL(router_fallback, dim3(n_tokens / 128), dim3(256),
                           0, stream, x, w1w, w1b, rb, out, n_tokens, dim);
    }
}

// Round 15
// 270.634 us; speedup vs baseline: 1.1942x; 1.1942x over previous
//
#include <hip/hip_runtime.h>
#include <math.h>

constexpr int NE = 16;   // experts
constexpr int NG = 4;    // groups
#define MARGIN 1e-4

typedef __attribute__((ext_vector_type(8))) short bf16x8;
typedef __attribute__((ext_vector_type(4))) float f32x4;

__device__ __forceinline__ unsigned short f2bf_rne(float f) {
    unsigned u = __float_as_uint(f);
    unsigned r = (u + 0x7fffu + ((u >> 16) & 1u)) >> 16;
    return (unsigned short)r;
}

__device__ __forceinline__ void gload_lds16(const float* g, float* l) {
    __builtin_amdgcn_global_load_lds(
        (const __attribute__((address_space(1))) void*)g,
        (__attribute__((address_space(3))) void*)l, 16, 0, 0);
}

// prep: wt fp32 [k][e] (for K2) + w split into bf16 hi/lo in ORIGINAL [e][k] layout
__global__ __launch_bounds__(256)
void w_prep_kernel(const float* __restrict__ w, float* __restrict__ wt,
                   unsigned short* __restrict__ whi, unsigned short* __restrict__ wlo,
                   int dim, int n) {
    int id = blockIdx.x * 256 + threadIdx.x;
    if (id < n) {
        int e = id / dim;
        int k = id - e * dim;
        float f = w[id];
        wt[(size_t)k * NE + e] = f;
        unsigned short h = f2bf_rne(f);
        float back = __uint_as_float(((unsigned)h) << 16);
        whi[id] = h;
        wlo[id] = f2bf_rne(f - back);
    }
}

struct RouteR { double v1, v2; int i1, i2; double mg, mo, ms; };

__device__ __forceinline__ RouteR route_epilogue(const double* tot,
                                                 const float* w1b,
                                                 const float* rbias)
{
    double logit[NE];
    double m = -INFINITY;
#pragma unroll
    for (int e = 0; e < NE; ++e) {
        logit[e] = tot[e] + (double)w1b[e];
        m = fmax(m, logit[e]);
    }
    double ssum = 0.0, p[NE];
#pragma unroll
    for (int e = 0; e < NE; ++e) { p[e] = exp(logit[e] - m); ssum += p[e]; }
    double inv = 1.0 / ssum, sc[NE];
#pragma unroll
    for (int e = 0; e < NE; ++e) sc[e] = p[e] * inv + (double)rbias[e];

    double gm[NG];
#pragma unroll
    for (int g = 0; g < NG; ++g) {
        double a = fmax(sc[g * 4 + 0], sc[g * 4 + 1]);
        double b = fmax(sc[g * 4 + 2], sc[g * 4 + 3]);
        gm[g] = fmax(a, b);
    }
    int g1 = 0;
#pragma unroll
    for (int g = 1; g < NG; ++g) if (gm[g] > gm[g1]) g1 = g;
    int g2 = (g1 == 0) ? 1 : 0;
#pragma unroll
    for (int g = 0; g < NG; ++g) if (g != g1 && gm[g] > gm[g2]) g2 = g;
    double gm3 = -INFINITY;
#pragma unroll
    for (int g = 0; g < NG; ++g)
        if (g != g1 && g != g2 && gm[g] > gm3) gm3 = gm[g];

    RouteR r;
    r.v1 = -INFINITY; r.i1 = 0;
#pragma unroll
    for (int e = 0; e < NE; ++e) {
        int g = e >> 2;
        bool keep = (g == g1) || (g == g2);
        if (keep && sc[e] > r.v1) { r.v1 = sc[e]; r.i1 = e; }
    }
    r.v2 = -INFINITY; r.i2 = 0;
#pragma unroll
    for (int e = 0; e < NE; ++e) {
        int g = e >> 2;
        bool keep = ((g == g1) || (g == g2)) && (e != r.i1);
        if (keep && sc[e] > r.v2) { r.v2 = sc[e]; r.i2 = e; }
    }
    double v3 = -INFINITY;
#pragma unroll
    for (int e = 0; e < NE; ++e) {
        int g = e >> 2;
        bool keep = ((g == g1) || (g == g2)) && (e != r.i1) && (e != r.i2);
        if (keep && sc[e] > v3) v3 = sc[e];
    }
    r.mg = gm[g2] - gm3;
    r.mo = r.v1 - r.v2;
    r.ms = r.v2 - v3;
    return r;
}

// K1: bf16-split MFMA with wave-contiguous LDS staging.
// Block: 4 waves, 16 tokens. Per step: [16 tok x 256 dim] tile, one
// global_load_lds instruction = one contiguous 1 KB row-chunk. Waves K-split
// the 256-dim chunk (64 dims each); counted vmcnt(8); raw s_barrier.
__global__ __launch_bounds__(256)
void k1_mfma(const float* __restrict__ x,
             const unsigned short* __restrict__ whi,
             const unsigned short* __restrict__ wlo,
             const float* __restrict__ w1b,
             const float* __restrict__ rbias,
             float* __restrict__ dout,
             int* __restrict__ fcount,
             int* __restrict__ flist,
             int n_tokens, int dim)
{
    __shared__ float tile[2][16][260];   // 33280 B, pad 4 floats/row
    const int tid  = threadIdx.x;
    const int uw   = __builtin_amdgcn_readfirstlane(tid >> 6);  // K-slice id
    const int lane = tid & 63;
    const int m    = lane & 15;          // A row (token) & B col (expert)
    const int kg   = lane >> 4;          // k-group
    const long tok0 = (long)blockIdx.x * 16;
    const int nst = dim / 256;           // 16 steps

    const unsigned short* whp = whi + (size_t)m * dim + uw * 64 + kg * 8;
    const unsigned short* wlp = wlo + (size_t)m * dim + uw * 64 + kg * 8;

    f32x4 acc = {0.f, 0.f, 0.f, 0.f};

    // prologue: B(0) regs + stage(0) -> buf0
    bf16x8 bh0 = *(const bf16x8*)(whp);
    bf16x8 bh1 = *(const bf16x8*)(whp + 32);
    bf16x8 bl0 = *(const bf16x8*)(wlp);
    bf16x8 bl1 = *(const bf16x8*)(wlp + 32);
#pragma unroll
    for (int i = 0; i < 4; ++i)
        gload_lds16(x + (tok0 + uw * 4 + i) * (size_t)dim + lane * 4,
                    &tile[0][uw * 4 + i][0]);

    int cur = 0;
    for (int s = 0; s < nst; ++s) {
        bf16x8 nbh0 = bh0, nbh1 = bh1, nbl0 = bl0, nbl1 = bl1;
        if (s + 1 < nst) {
            const unsigned short* wh2 = whp + (size_t)(s + 1) * 256;
            const unsigned short* wl2 = wlp + (size_t)(s + 1) * 256;
            nbh0 = *(const bf16x8*)(wh2);
            nbh1 = *(const bf16x8*)(wh2 + 32);
            nbl0 = *(const bf16x8*)(wl2);
            nbl1 = *(const bf16x8*)(wl2 + 32);
#pragma unroll
            for (int i = 0; i < 4; ++i)
                gload_lds16(x + (tok0 + uw * 4 + i) * (size_t)dim
                              + (size_t)(s + 1) * 256 + lane * 4,
                            &tile[cur ^ 1][uw * 4 + i][0]);
            __builtin_amdgcn_sched_barrier(0);
            asm volatile("s_waitcnt vmcnt(8)" ::: "memory");  // prev step landed
            __builtin_amdgcn_sched_barrier(0);
        } else {
            __builtin_amdgcn_sched_barrier(0);
            asm volatile("s_waitcnt vmcnt(0)" ::: "memory");
            __builtin_amdgcn_sched_barrier(0);
        }
        __builtin_amdgcn_s_barrier();
        __builtin_amdgcn_sched_barrier(0);

#pragma unroll
        for (int it = 0; it < 2; ++it) {
            const float* ap = &tile[cur][m][uw * 64 + kg * 8 + it * 32];
            float4 xa = *(const float4*)ap;         // ds_read_b128
            float4 xb = *(const float4*)(ap + 4);   // ds_read_b128
            float xf[8] = {xa.x, xa.y, xa.z, xa.w, xb.x, xb.y, xb.z, xb.w};
            bf16x8 xhi, xlo;
#pragma unroll
            for (int j = 0; j < 8; ++j) {
                float f = xf[j];
                unsigned short h = f2bf_rne(f);
                float back = __uint_as_float(((unsigned)h) << 16);
                xhi[j] = (short)h;
                xlo[j] = (short)f2bf_rne(f - back);
            }
            bf16x8 wh = it ? bh1 : bh0;
            bf16x8 wl = it ? bl1 : bl0;
            acc = __builtin_amdgcn_mfma_f32_16x16x32_bf16(xhi, wh, acc, 0, 0, 0);
            acc = __builtin_amdgcn_mfma_f32_16x16x32_bf16(xlo, wh, acc, 0, 0, 0);
            acc = __builtin_amdgcn_mfma_f32_16x16x32_bf16(xhi, wl, acc, 0, 0, 0);
        }
        __builtin_amdgcn_sched_barrier(0);
        __builtin_amdgcn_s_barrier();   // protect buf before next overwrite
        __builtin_amdgcn_sched_barrier(0);
        bh0 = nbh0; bh1 = nbh1; bl0 = nbl0; bl1 = nbl1;
        cur ^= 1;
    }

    // cross-wave K-slice reduction (alias tile memory; loop's last barrier synced)
    float (*red)[16][17] = (float (*)[16][17])(&tile[0][0][0]);
#pragma unroll
    for (int j = 0; j < 4; ++j)
        red[uw][kg * 4 + j][m] = acc[j];   // D: row=kg*4+j (token), col=m (expert)
    __syncthreads();

    if (uw == 0 && lane < 16) {
        double tot[NE];
#pragma unroll
        for (int e = 0; e < NE; ++e)
            tot[e] = (((double)red[0][lane][e] + (double)red[1][lane][e])
                      + (double)red[2][lane][e]) + (double)red[3][lane][e];
        RouteR r = route_epilogue(tot, w1b, rbias);
        long tok = tok0 + lane;

        double mmin = fmin(r.mg, fmin(r.mo, r.ms));
        if (mmin < MARGIN) {
            int idx = atomicAdd(fcount, 1);
            if (idx < n_tokens) flist[idx] = (int)tok;
        }
        float2 vv; vv.x = (float)r.v1; vv.y = (float)r.v2;
        *(float2*)(dout + tok * 2) = vv;
        float2 iv; iv.x = (float)r.i1; iv.y = (float)r.i2;
        *(float2*)(dout + (long)n_tokens * 2 + tok * 2) = iv;
    }
}

// K2: authoritative fp64 recompute, one wave per flagged token (proven r12-14)
__global__ __launch_bounds__(256)
void k2_recheck(const float* __restrict__ x,
                const float* __restrict__ wt,
                const float* __restrict__ w1b,
                const float* __restrict__ rbias,
                float* __restrict__ dout,
                const int* __restrict__ fcount,
                const int* __restrict__ flist,
                int n_tokens, int dim)
{
    const int tid  = threadIdx.x;
    const int lane = tid & 63;
    const int wavesPerBlock = blockDim.x >> 6;
    const int wglobal = blockIdx.x * wavesPerBlock + (tid >> 6);
    const int nwaves  = gridDim.x * wavesPerBlock;
    int nf = *fcount;
    if (nf > n_tokens) nf = n_tokens;
    const int nq = dim / 256;

    for (int i = wglobal; i < nf; i += nwaves) {
        const int t = flist[i];
        const float* xr = x + (size_t)t * dim;

        double part[NE];
#pragma unroll
        for (int e = 0; e < NE; ++e) part[e] = 0.0;

        for (int q = 0; q < nq; ++q) {
            float4 xv = *(const float4*)(xr + q * 256 + lane * 4);
#pragma unroll
            for (int j = 0; j < 4; ++j) {
                int k = q * 256 + lane * 4 + j;
                double xd = (double)((const float*)&xv)[j];
                const float* wr = wt + (size_t)k * NE;
#pragma unroll
                for (int e = 0; e < NE; ++e)
                    part[e] = fma(xd, (double)wr[e], part[e]);
            }
        }

#pragma unroll
        for (int off = 1; off < 64; off <<= 1) {
#pragma unroll
            for (int e = 0; e < NE; ++e)
                part[e] += __shfl_xor(part[e], off, 64);
        }

        RouteR r = route_epilogue(part, w1b, rbias);
        if (lane == 0) {
            float2 vv; vv.x = (float)r.v1; vv.y = (float)r.v2;
            *(float2*)(dout + (long)t * 2) = vv;
            float2 iv; iv.x = (float)r.i1; iv.y = (float)r.i2;
            *(float2*)(dout + (long)n_tokens * 2 + (long)t * 2) = iv;
        }
    }
}

// ---------------- fallback (round-9 proven fp64 structure, w gathered) ------
__global__ __launch_bounds__(256)
void router_fallback(const float* __restrict__ x,
                     const float* __restrict__ w1w,
                     const float* __restrict__ w1b,
                     const float* __restrict__ rbias,
                     float* __restrict__ dout,
                     int n_tokens, int dim)
{
    __shared__ double wbuf4[4][16][NE];
    const int tid  = threadIdx.x;
    const int uwid = __builtin_amdgcn_readfirstlane(tid >> 6);
    const int lane = tid & 63;
    const int slice = dim / 4;
    const int nst  = slice / 16;
    const long tokA = (long)blockIdx.x * 128 + lane;
    const long tokB = tokA + 64;
    const float* xA = x + tokA * (size_t)dim + (size_t)uwid * slice;
    const float* xB = x + tokB * (size_t)dim + (size_t)uwid * slice;

    double accA[NE], accB[NE];
#pragma unroll
    for (int e = 0; e < NE; ++e) { accA[e] = 0.0; accB[e] = 0.0; }

    float4 a0 = *(const float4*)(xA + 0), a1 = *(const float4*)(xA + 4);
    float4 a2 = *(const float4*)(xA + 8), a3 = *(const float4*)(xA + 12);
    float4 b0 = *(const float4*)(xB + 0), b1 = *(const float4*)(xB + 4);
    float4 b2 = *(const float4*)(xB + 8), b3 = *(const float4*)(xB + 12);
    float4 wreg;
    {
        const int i0 = lane * 4;
#pragma unroll
        for (int j = 0; j < 4; ++j) {
            int i = i0 + j;
            ((float*)&wreg)[j] = w1w[(size_t)(i & 15) * dim + uwid * slice + (i >> 4)];
        }
    }

    for (int c = 0; c < nst; ++c) {
        {
            double* dst = &wbuf4[uwid][0][0] + lane * 4;
            dst[0] = (double)wreg.x;  dst[1] = (double)wreg.y;
            dst[2] = (double)wreg.z;  dst[3] = (double)wreg.w;
        }
        float4 na0=a0,na1=a1,na2=a2,na3=a3,nb0=b0,nb1=b1,nb2=b2,nb3=b3;
        if (c + 1 < nst) {
            const float* pa = xA + (c + 1) * 16;
            const float* pb = xB + (c + 1) * 16;
            na0 = *(const float4*)(pa + 0);  na1 = *(const float4*)(pa + 4);
            na2 = *(const float4*)(pa + 8);  na3 = *(const float4*)(pa + 12);
            nb0 = *(const float4*)(pb + 0);  nb1 = *(const float4*)(pb + 4);
            nb2 = *(const float4*)(pb + 8);  nb3 = *(const float4*)(pb + 12);
            const int kb = uwid * slice + (c + 1) * 16;
            const int i0 = lane * 4;
#pragma unroll
            for (int j = 0; j < 4; ++j) {
                int i = i0 + j;
                ((float*)&wreg)[j] = w1w[(size_t)(i & 15) * dim + kb + (i >> 4)];
            }
        }
        float fa[16], fb[16];
        fa[0]=a0.x; fa[1]=a0.y; fa[2]=a0.z; fa[3]=a0.w;
        fa[4]=a1.x; fa[5]=a1.y; fa[6]=a1.z; fa[7]=a1.w;
        fa[8]=a2.x; fa[9]=a2.y; fa[10]=a2.z; fa[11]=a2.w;
        fa[12]=a3.x; fa[13]=a3.y; fa[14]=a3.z; fa[15]=a3.w;
        fb[0]=b0.x; fb[1]=b0.y; fb[2]=b0.z; fb[3]=b0.w;
        fb[4]=b1.x; fb[5]=b1.y; fb[6]=b1.z; fb[7]=b1.w;
        fb[8]=b2.x; fb[9]=b2.y; fb[10]=b2.z; fb[11]=b2.w;
        fb[12]=b3.x; fb[13]=b3.y; fb[14]=b3.z; fb[15]=b3.w;
#pragma unroll
        for (int kk = 0; kk < 16; ++kk) {
            double xa_ = (double)fa[kk];
            double xb_ = (double)fb[kk];
#pragma unroll
            for (int ep = 0; ep < NE / 2; ++ep) {
                double2 wv = *(const double2*)&wbuf4[uwid][kk][ep * 2];
                accA[ep*2+0] = fma(xa_, wv.x, accA[ep*2+0]);
                accA[ep*2+1] = fma(xa_, wv.y, accA[ep*2+1]);
                accB[ep*2+0] = fma(xb_, wv.x, accB[ep*2+0]);
                accB[ep*2+1] = fma(xb_, wv.y, accB[ep*2+1]);
            }
        }
        a0=na0; a1=na1; a2=na2; a3=na3;
        b0=nb0; b1=nb1; b2=nb2; b3=nb3;
    }

    __syncthreads();
    __shared__ double red[3][2][64][NE + 1];
    if (uwid != 0) {
#pragma unroll
        for (int e = 0; e < NE; ++e) {
            red[uwid - 1][0][lane][e] = accA[e];
            red[uwid - 1][1][lane][e] = accB[e];
        }
    }
    __syncthreads();
    if (uwid != 0) return;

#pragma unroll
    for (int t = 0; t < 2; ++t) {
        double tot[NE];
#pragma unroll
        for (int e = 0; e < NE; ++e) {
            double a = (t == 0) ? accA[e] : accB[e];
            tot[e] = ((a + red[0][t][lane][e]) + red[1][t][lane][e])
                     + red[2][t][lane][e];
        }
        RouteR r = route_epilogue(tot, w1b, rbias);
        long tok = (t == 0) ? tokA : tokB;
        float2 vv; vv.x = (float)r.v1; vv.y = (float)r.v2;
        *(float2*)(dout + tok * 2) = vv;
        float2 iv; iv.x = (float)r.i1; iv.y = (float)r.i2;
        *(float2*)(dout + (long)n_tokens * 2 + tok * 2) = iv;
    }
}

extern "C" void kernel_launch(void* const* d_in, const int* in_sizes, int n_in,
                              void* d_out, int out_size, void* d_ws, size_t ws_size,
                              hipStream_t stream)
{
    const float* x   = (const float*)d_in[0];
    const float* w1w = (const float*)d_in[1];
    const float* w1b = (const float*)d_in[2];
    const float* rb  = (const float*)d_in[3];
    float* out = (float*)d_out;

    const int ne       = in_sizes[2];            // 16
    const int dim      = in_sizes[1] / ne;       // 4096
    const int n_tokens = in_sizes[0] / dim;      // 65536

    const int nW = dim * ne;                     // 65536 w elements
    const size_t WT_BYTES  = (size_t)nW * sizeof(float);          // 256 KB
    const size_t WHI_OFF   = WT_BYTES;
    const size_t WLO_OFF   = WHI_OFF + (size_t)nW * 2;            // +128 KB
    const size_t COUNT_OFF = WLO_OFF + (size_t)nW * 2;            // +128 KB
    const size_t LIST_OFF  = COUNT_OFF + 128;
    const size_t need = LIST_OFF + (size_t)n_tokens * sizeof(int);

    if (ws_size >= need) {
        float* wt            = (float*)d_ws;
        unsigned short* whi  = (unsigned short*)((char*)d_ws + WHI_OFF);
        unsigned short* wlo  = (unsigned short*)((char*)d_ws + WLO_OFF);
        int* fcount          = (int*)((char*)d_ws + COUNT_OFF);
        int* flist           = (int*)((char*)d_ws + LIST_OFF);

        hipMemsetAsync(fcount, 0, sizeof(int), stream);
        hipLaunchKernelGGL(w_prep_kernel, dim3((nW + 255) / 256), dim3(256),
                           0, stream, w1w, wt, whi, wlo, dim, nW);
        hipLaunchKernelGGL(k1_mfma, dim3(n_tokens / 16), dim3(256),
                           0, stream, x, whi, wlo, w1b, rb, out, fcount, flist,
                           n_tokens, dim);
        hipLaunchKernelGGL(k2_recheck, dim3(256), dim3(256),
                           0, stream, x, wt, w1b, rb, out, fcount, flist,
                           n_tokens, dim);
    } else {
        hipLaunchKernelGGL(router_fallback, dim3(n_tokens / 128), dim3(256),
                           0, stream, x, w1w, w1b, rb, out, n_tokens, dim);
    }
}